// Round 1
// baseline (58.667 us; speedup 1.0000x reference)
//
#include <hip/hip_runtime.h>

// Problem shape (fixed by the reference):
//   k_cache/v_cache : (B, H, S, D)      f32
//   k_val/v_val     : (B, H, S_NEW, D)  f32
//   input_pos       : (S_NEW,)          i32  (distinct positions in [0,S))
//   flatten_index   : (B*H*HC,)         i32  (rows into the (B*H*S, D) view)
//   out             : [2, B, H, HC, D]  f32  (stacked K/V gathers AFTER scatter)
constexpr int B     = 4;
constexpr int H     = 32;
constexpr int S     = 4096;   // power of two: 2^12
constexpr int D     = 128;
constexpr int HC    = 1024;
constexpr int S_NEW = 512;

constexpr int NROWS = B * H * HC;     // 131072 = 2^17 gathered rows per tensor
constexpr int VPR   = D / 4;          // 32 float4 per row
constexpr int LOG_VPR   = 5;
constexpr int LOG_NROWS = 17;
constexpr int LOG_S     = 12;

// Kernel 1: build inverse position map pos2slot[s] = i if input_pos[i]==s else -1.
// Single block so init + scatter can be ordered with one __syncthreads().
__global__ void build_inverse_map(const int* __restrict__ input_pos,
                                  int* __restrict__ pos2slot) {
    for (int i = threadIdx.x; i < S; i += blockDim.x) pos2slot[i] = -1;
    __syncthreads();
    if (threadIdx.x < S_NEW) pos2slot[input_pos[threadIdx.x]] = (int)threadIdx.x;
}

// Kernel 2: fused "virtual scatter" + gather.
// Thread tid handles one float4 of the output:
//   vec    = tid & 31            (float4 within the row)
//   row    = (tid>>5) & (NROWS-1)
//   tensor = tid >> 22           (0 = K, 1 = V)
// 32 consecutive lanes (half-wave) stream one contiguous 512 B row.
__global__ __launch_bounds__(256) void gather_kernel(
    const float4* __restrict__ k_cache, const float4* __restrict__ v_cache,
    const float4* __restrict__ k_val,   const float4* __restrict__ v_val,
    const int* __restrict__ fidx, const int* __restrict__ pos2slot,
    float4* __restrict__ out)
{
    unsigned tid    = blockIdx.x * blockDim.x + threadIdx.x; // < 2*NROWS*VPR = 8388608
    unsigned vec    = tid & (VPR - 1);
    unsigned rowt   = tid >> LOG_VPR;
    unsigned row    = rowt & (NROWS - 1);
    unsigned tensor = rowt >> LOG_NROWS;     // 0 or 1

    int r  = fidx[row];                       // flat row in (B*H*S)
    int s  = r & (S - 1);                     // seq position
    int bh = r >> LOG_S;                      // b*H + h in [0, B*H)

    int slot = pos2slot[s];                   // >=0 iff this position was overwritten

    const float4* src;
    if (slot >= 0) {
        const float4* base = tensor ? v_val : k_val;
        src = base + ((size_t)bh * S_NEW + (size_t)slot) * VPR + vec;
    } else {
        const float4* base = tensor ? v_cache : k_cache;
        src = base + (size_t)r * VPR + vec;
    }
    out[tid] = *src;
}

extern "C" void kernel_launch(void* const* d_in, const int* in_sizes, int n_in,
                              void* d_out, int out_size, void* d_ws, size_t ws_size,
                              hipStream_t stream) {
    const float* k_cache  = (const float*)d_in[0];
    const float* v_cache  = (const float*)d_in[1];
    const float* k_val    = (const float*)d_in[2];
    const float* v_val    = (const float*)d_in[3];
    const int*   input_pos = (const int*)d_in[4];
    const int*   fidx      = (const int*)d_in[5];
    float*       out       = (float*)d_out;

    int* pos2slot = (int*)d_ws;   // S ints = 16 KiB scratch

    build_inverse_map<<<1, 512, 0, stream>>>(input_pos, pos2slot);

    unsigned total_threads = 2u * NROWS * VPR;       // 8,388,608
    unsigned blocks = total_threads / 256u;          // 32768
    gather_kernel<<<blocks, 256, 0, stream>>>(
        (const float4*)k_cache, (const float4*)v_cache,
        (const float4*)k_val,   (const float4*)v_val,
        fidx, pos2slot, (float4*)out);
}

// Round 2
// 49.591 us; speedup vs baseline: 1.1830x; 1.1830x over previous
//
#include <hip/hip_runtime.h>

// Problem shape (fixed by the reference):
//   k_cache/v_cache : (B, H, S, D)      f32
//   k_val/v_val     : (B, H, S_NEW, D)  f32
//   input_pos       : (S_NEW,)          i32  (distinct positions in [0,S))
//   flatten_index   : (B*H*HC,)         i32  (rows into the (B*H*S, D) view)
//   out             : [2, B, H, HC, D]  f32  (stacked K/V gathers AFTER scatter)
constexpr int B     = 4;
constexpr int H     = 32;
constexpr int S     = 4096;   // 2^12
constexpr int D     = 128;
constexpr int HC    = 1024;
constexpr int S_NEW = 512;

constexpr int NROWS = B * H * HC;     // 131072 = 2^17 gathered rows per tensor
constexpr int VPR   = D / 4;          // 32 float4 per row
constexpr int LOG_VPR   = 5;
constexpr int LOG_S     = 12;
constexpr unsigned TOTAL = (unsigned)NROWS * VPR;   // 4,194,304 threads (K+V fused)

typedef float f32x4 __attribute__((ext_vector_type(4)));

// Kernel 1: inverse position map pos2slot[s] = i if input_pos[i]==s else -1.
// Single block so init + scatter order with one __syncthreads().
__global__ void build_inverse_map(const int* __restrict__ input_pos,
                                  int* __restrict__ pos2slot) {
    for (int i = threadIdx.x; i < S; i += blockDim.x) pos2slot[i] = -1;
    __syncthreads();
    if (threadIdx.x < S_NEW) pos2slot[input_pos[threadIdx.x]] = (int)threadIdx.x;
}

// Kernel 2: fused virtual-scatter + gather, K and V in the same thread.
// Thread tid: vec = tid&31 (float4 within row), row = tid>>5.
// 32 consecutive lanes stream one contiguous 512 B row of each tensor.
// Two independent loads per thread (K-row, V-row) for memory-level parallelism.
// Nontemporal stores: out is write-once, keep it out of L2 so k_val/v_val and
// duplicate-row reads stay cached.
__global__ __launch_bounds__(256) void gather_kernel(
    const f32x4* __restrict__ k_cache, const f32x4* __restrict__ v_cache,
    const f32x4* __restrict__ k_val,   const f32x4* __restrict__ v_val,
    const int* __restrict__ fidx, const int* __restrict__ pos2slot,
    f32x4* __restrict__ out)
{
    unsigned tid = blockIdx.x * blockDim.x + threadIdx.x;  // < TOTAL
    unsigned vec = tid & (VPR - 1);
    unsigned row = tid >> LOG_VPR;            // [0, NROWS)

    int r  = fidx[row];                       // flat row in (B*H*S)
    int s  = r & (S - 1);                     // seq position
    int bh = r >> LOG_S;                      // b*H + h

    int slot = pos2slot[s];                   // >=0 iff position was overwritten

    const f32x4* ksrc;
    const f32x4* vsrc;
    if (slot >= 0) {
        size_t off = ((size_t)bh * S_NEW + (size_t)slot) * VPR + vec;
        ksrc = k_val + off;
        vsrc = v_val + off;
    } else {
        size_t off = (size_t)r * VPR + vec;
        ksrc = k_cache + off;
        vsrc = v_cache + off;
    }
    f32x4 kq = *ksrc;                         // two independent in-flight loads
    f32x4 vq = *vsrc;
    __builtin_nontemporal_store(kq, out + tid);
    __builtin_nontemporal_store(vq, out + TOTAL + tid);
}

extern "C" void kernel_launch(void* const* d_in, const int* in_sizes, int n_in,
                              void* d_out, int out_size, void* d_ws, size_t ws_size,
                              hipStream_t stream) {
    const float* k_cache   = (const float*)d_in[0];
    const float* v_cache   = (const float*)d_in[1];
    const float* k_val     = (const float*)d_in[2];
    const float* v_val     = (const float*)d_in[3];
    const int*   input_pos = (const int*)d_in[4];
    const int*   fidx      = (const int*)d_in[5];
    f32x4*       out       = (f32x4*)d_out;

    int* pos2slot = (int*)d_ws;   // S ints = 16 KiB scratch

    build_inverse_map<<<1, 512, 0, stream>>>(input_pos, pos2slot);

    unsigned blocks = TOTAL / 256u;           // 16384
    gather_kernel<<<blocks, 256, 0, stream>>>(
        (const f32x4*)k_cache, (const f32x4*)v_cache,
        (const f32x4*)k_val,   (const f32x4*)v_val,
        fidx, pos2slot, out);
}

// Round 3
// 45.548 us; speedup vs baseline: 1.2880x; 1.0888x over previous
//
#include <hip/hip_runtime.h>

// Problem shape (fixed by the reference):
//   k_cache/v_cache : (B, H, S, D)      f32
//   k_val/v_val     : (B, H, S_NEW, D)  f32
//   input_pos       : (S_NEW,)          i32  (distinct positions in [0,S))
//   flatten_index   : (B*H*HC,)         i32  (rows into the (B*H*S, D) view)
//   out             : [2, B, H, HC, D]  f32  (stacked K/V gathers AFTER scatter)
constexpr int B     = 4;
constexpr int H     = 32;
constexpr int S     = 4096;   // 2^12
constexpr int D     = 128;
constexpr int HC    = 1024;
constexpr int S_NEW = 512;

constexpr int NROWS = B * H * HC;                  // 131072 rows per tensor
constexpr int VPR   = D / 4;                       // 32 float4 per row
constexpr int LOG_VPR = 5;
constexpr int LOG_S   = 12;
constexpr unsigned TOTAL = (unsigned)NROWS * VPR;  // 4,194,304 vec-slots per tensor
constexpr unsigned HALF  = TOTAL / 2;
constexpr int BLOCK = 256;

typedef float f32x4 __attribute__((ext_vector_type(4)));

// Single fused kernel: per-block LDS inverse map + virtual-scatter gather.
// Each thread handles TWO (row, vec) slots -> 4 independent 16B loads + 4 NT
// stores, for memory-level parallelism. 32 consecutive lanes stream one
// contiguous 512 B row; stores are fully coalesced.
__global__ __launch_bounds__(BLOCK) void fused_gather(
    const f32x4* __restrict__ k_cache, const f32x4* __restrict__ v_cache,
    const f32x4* __restrict__ k_val,   const f32x4* __restrict__ v_val,
    const int* __restrict__ input_pos, const int* __restrict__ fidx,
    f32x4* __restrict__ out)
{
    // Build pos2slot in LDS (16 KiB). input_pos is 2 KB, L2-resident after the
    // first few blocks -> negligible HBM cost for the redundancy.
    __shared__ int p2s[S];
    #pragma unroll
    for (int i = threadIdx.x; i < S; i += BLOCK) p2s[i] = -1;
    __syncthreads();
    #pragma unroll
    for (int i = threadIdx.x; i < S_NEW; i += BLOCK) p2s[input_pos[i]] = i;
    __syncthreads();

    unsigned tid  = blockIdx.x * BLOCK + threadIdx.x;   // [0, HALF)
    unsigned vec  = tid & (VPR - 1);
    unsigned row0 = tid >> LOG_VPR;                     // [0, NROWS/2)
    unsigned row1 = row0 + (NROWS >> 1);

    int r0 = fidx[row0];
    int r1 = fidx[row1];
    int s0 = r0 & (S - 1),  s1 = r1 & (S - 1);
    int bh0 = r0 >> LOG_S,  bh1 = r1 >> LOG_S;
    int sl0 = p2s[s0],      sl1 = p2s[s1];              // wave-broadcast LDS reads

    size_t o0 = (sl0 >= 0) ? ((size_t)bh0 * S_NEW + (size_t)sl0) * VPR + vec
                           : (size_t)r0 * VPR + vec;
    size_t o1 = (sl1 >= 0) ? ((size_t)bh1 * S_NEW + (size_t)sl1) * VPR + vec
                           : (size_t)r1 * VPR + vec;
    const f32x4* kb0 = (sl0 >= 0) ? k_val : k_cache;
    const f32x4* vb0 = (sl0 >= 0) ? v_val : v_cache;
    const f32x4* kb1 = (sl1 >= 0) ? k_val : k_cache;
    const f32x4* vb1 = (sl1 >= 0) ? v_val : v_cache;

    // 4 independent in-flight loads
    f32x4 kq0 = kb0[o0];
    f32x4 kq1 = kb1[o1];
    f32x4 vq0 = vb0[o0];
    f32x4 vq1 = vb1[o1];

    // out index for (tensor, row, vec) = tensor*TOTAL + row*VPR + vec
    __builtin_nontemporal_store(kq0, out + tid);
    __builtin_nontemporal_store(kq1, out + HALF + tid);
    __builtin_nontemporal_store(vq0, out + TOTAL + tid);
    __builtin_nontemporal_store(vq1, out + TOTAL + HALF + tid);
}

extern "C" void kernel_launch(void* const* d_in, const int* in_sizes, int n_in,
                              void* d_out, int out_size, void* d_ws, size_t ws_size,
                              hipStream_t stream) {
    const float* k_cache   = (const float*)d_in[0];
    const float* v_cache   = (const float*)d_in[1];
    const float* k_val     = (const float*)d_in[2];
    const float* v_val     = (const float*)d_in[3];
    const int*   input_pos = (const int*)d_in[4];
    const int*   fidx      = (const int*)d_in[5];
    f32x4*       out       = (f32x4*)d_out;

    unsigned blocks = HALF / BLOCK;   // 8192
    fused_gather<<<blocks, BLOCK, 0, stream>>>(
        (const f32x4*)k_cache, (const f32x4*)v_cache,
        (const f32x4*)k_val,   (const f32x4*)v_val,
        input_pos, fidx, out);
}